// Round 8
// baseline (170.500 us; speedup 1.0000x reference)
//
#include <hip/hip_runtime.h>
#include <hip/hip_bf16.h>
#include <math.h>

#define FDIM 6272
#define LQ   256
#define BN   8
#define UDIM 32
#define BL   (BN*LQ)        // 2048
#define QG   4              // q-rows per k2 block (Tk-staging amortization)

typedef short  short8 __attribute__((ext_vector_type(8)));
typedef float  f32x4  __attribute__((ext_vector_type(4)));

static __device__ __forceinline__ ushort f2bf(float f) {
    __hip_bfloat16 h = __float2bfloat16(f);
    return *(ushort*)&h;
}
// raw transcendentals (v_exp_f32 = 2^x); s_nop covers the TRANS-op hazard
static __device__ __forceinline__ float fexp2(float x) {
    float r;
    asm volatile("v_exp_f32 %0, %1 \n s_nop 1" : "=v"(r) : "v"(x));
    return r;
}
static __device__ __forceinline__ float frcp(float x) {
    float r;
    asm volatile("v_rcp_f32 %0, %1 \n s_nop 1" : "=v"(r) : "v"(x));
    return r;
}

// ---------------------------------------------------------------------------
// Kw: Wtt[u][f] = bf16(Wt[f][u]) + zero pb. grid 98 x 256.
// ---------------------------------------------------------------------------
__global__ __launch_bounds__(256)
void k_wtt(const float* __restrict__ Wt, ushort* __restrict__ wtt,
           float* __restrict__ pb) {
    const int gid = blockIdx.x * 256 + threadIdx.x;   // 0..25087
    const int u = gid / 784, fg = gid % 784;
    ushort v[8];
    #pragma unroll
    for (int j = 0; j < 8; ++j)
        v[j] = f2bf(Wt[(size_t)(8 * fg + j) * UDIM + u]);
    *(uint4*)(wtt + (size_t)u * FDIM + 8 * fg) = *(uint4*)v;

    if (gid < BL * UDIM / 4)
        ((float4*)pb)[gid] = make_float4(0.f, 0.f, 0.f, 0.f);
}

// ---------------------------------------------------------------------------
// K1: pb[row][u] += sum_f x[row][f]*Wt[f][u], bf16 MFMA, NO LDS/barriers.
// Fragments direct from global in MFMA operand order. Byproduct: waves 0-1
// store packed A-frags as xb16[row][f] for K3. f-split 14 (896 blocks =
// 3.5/CU) for streaming-load latency hiding. grid (64, 14), block 256.
// ---------------------------------------------------------------------------
__global__ __launch_bounds__(256)
void k1_mfma(const float* __restrict__ x, const ushort* __restrict__ wtt,
             float* __restrict__ pb, ushort* __restrict__ xb16) {
    const int t    = threadIdx.x;
    const int wv   = t >> 6, lane = t & 63;
    const int n16  = lane & 15, quad = lane >> 4;
    const int row0 = blockIdx.x * 32 + 16 * (wv & 1);
    const int u0   = 16 * (wv >> 1);
    const int f0   = blockIdx.y * 448;

    const float*  xr = x    + (size_t)(row0 + n16) * FDIM + f0 + quad * 8;
    const ushort* wr = wtt  + (size_t)(u0   + n16) * FDIM + f0 + quad * 8;
    ushort*       xw = xb16 + (size_t)(row0 + n16) * FDIM + f0 + quad * 8;

    f32x4 acc = (f32x4){0.f, 0.f, 0.f, 0.f};

    #pragma unroll 7
    for (int c = 0; c < 14; ++c) {
        const float4 a0 = *(const float4*)(xr + c * 32);
        const float4 a1 = *(const float4*)(xr + c * 32 + 4);
        short8 af;
        af[0] = (short)f2bf(a0.x); af[1] = (short)f2bf(a0.y);
        af[2] = (short)f2bf(a0.z); af[3] = (short)f2bf(a0.w);
        af[4] = (short)f2bf(a1.x); af[5] = (short)f2bf(a1.y);
        af[6] = (short)f2bf(a1.z); af[7] = (short)f2bf(a1.w);
        if (wv < 2)                         // waves 2,3 duplicate rows: skip
            *(short8*)(xw + c * 32) = af;
        const short8 bf = *(const short8*)(wr + c * 32);
        acc = __builtin_amdgcn_mfma_f32_16x16x32_bf16(af, bf, acc, 0, 0, 0);
    }

    #pragma unroll
    for (int r = 0; r < 4; ++r)
        atomicAdd(&pb[(size_t)(row0 + quad * 4 + r) * UDIM + u0 + n16], acc[r]);
}

// ---------------------------------------------------------------------------
// K2: ab[b,q,:] = softmax_k sigmoid( sum_u tanh(pq+pk+bh)*Wa + ba )
// Identity: tanh(pq_u+bh_u+pk_u) = 1 - 2/(1 + Tq_u*Tk_u),
//   Tq = 2^(K(pq+bh)), Tk = 2^(K pk), K = 2/ln2.
// Tk staged (exp ONCE per (k,u) per block) and reused across QG=4 q-rows:
// trans-ops/thread 256 -> 160; inner loop 3 instr/u (fma+rcp+fma).
// grid (64 q-groups, 8 b), block 256 (thread = k).
// ---------------------------------------------------------------------------
__global__ __launch_bounds__(256)
void k2_attn(const float* __restrict__ pb, const float* __restrict__ bh,
             const float* __restrict__ Wa, const float* __restrict__ ba,
             ushort* __restrict__ ab) {
    const int b  = blockIdx.y;
    const int q0 = blockIdx.x * QG;
    const int k  = threadIdx.x;

    __shared__ float tk_s[LQ * 33];      // Tk, padded rows (2-way banks, free)
    __shared__ float tq_s[UDIM];
    __shared__ float wa2_s[UDIM];
    __shared__ float ebh_s[UDIM];
    __shared__ float swa_s;
    __shared__ float red[4];

    const float KL = 2.88539008177793f;  // 2/ln2

    if (k < UDIM) { wa2_s[k] = 2.f * Wa[k]; ebh_s[k] = fexp2(KL * bh[k]); }
    if (k < 64) {                        // swa = sum_u Wa[u] via wave reduce
        float v = (k < UDIM) ? Wa[k] : 0.f;
        #pragma unroll
        for (int m = 1; m < 64; m <<= 1) v += __shfl_xor(v, m, 64);
        if (k == 0) swa_s = v;
    }
    const float* pbb = pb + (size_t)b * LQ * UDIM;
    #pragma unroll
    for (int i = 0; i < 32; ++i) {
        const int idx = k + i * 256;
        tk_s[(idx >> 5) * 33 + (idx & 31)] = fexp2(KL * pbb[idx]);
    }
    __syncthreads();

    const float  swa = swa_s;
    const float* tk  = &tk_s[k * 33];

    for (int qi = 0; qi < QG; ++qi) {
        const int q = q0 + qi;
        if (k < UDIM) tq_s[k] = ebh_s[k] * tk_s[q * 33 + k];
        __syncthreads();

        float sacc = 0.f;
        #pragma unroll
        for (int u = 0; u < UDIM; ++u)
            sacc = fmaf(wa2_s[u], frcp(fmaf(tq_s[u], tk[u], 1.f)), sacc);
        const float s = swa - sacc;      // = sum_u Wa_u * tanh(...)

        const float alpha = frcp(1.f + fexp2(-(s + ba[0]) * 1.44269504088896f));
        const float e = fexp2(alpha * 1.44269504088896f);   // sigmoid in (0,1)

        float v = e;
        #pragma unroll
        for (int m = 1; m < 64; m <<= 1) v += __shfl_xor(v, m, 64);
        if ((k & 63) == 0) red[k >> 6] = v;
        __syncthreads();
        const float tot = red[0] + red[1] + red[2] + red[3];

        ab[((size_t)b * LQ + q) * LQ + k] = f2bf(e * frcp(tot));
        __syncthreads();                 // red/tq_s safe for next qi
    }
}

// ---------------------------------------------------------------------------
// K3: out[b,q,f] = sum_k a[b,q,k]*x[b,k,f], bf16 MFMA, staging from xb16.
// BK=64 double-buffered LDS, one barrier per chunk, prefetch in flight.
// A-frags direct from global (ab L2-hot). Bs rows stride 72 ushort
// (9x16B, odd -> conflict-free b128 frags). grid (98 f-tiles, 8 b).
// ---------------------------------------------------------------------------
__global__ __launch_bounds__(256)
void k3_fused(const ushort* __restrict__ xb16, const ushort* __restrict__ ab,
              float* __restrict__ out) {
    __shared__ ushort Bs[2][64 * 72];    // 2 x 9 KB

    const int t    = threadIdx.x;
    const int f0   = blockIdx.x * 64;
    const int b    = blockIdx.y;
    const int wv   = t >> 6;
    const int lane = t & 63;
    const int n16  = lane & 15;
    const int quad = lane >> 4;
    const int g    = t >> 4;             // f-quad 0..15
    const int kp   = t & 15;             // k-pair slot 0..15 (handles kp, kp+16)

    const ushort* xb  = xb16 + (size_t)b * LQ * FDIM + f0 + 4 * g;
    const ushort* abb = ab   + (size_t)b * LQ * LQ;

    f32x4 acc[4][4];
    #pragma unroll
    for (int mf = 0; mf < 4; ++mf)
        #pragma unroll
        for (int nf = 0; nf < 4; ++nf)
            acc[mf][nf] = (f32x4){0.f, 0.f, 0.f, 0.f};

    uint2 r0, r1, r2, r3;                // rows 2kp, 2kp+1, 2kp+32, 2kp+33
#define LDX(kc) do {                                                      \
        r0 = *(const uint2*)(xb + (size_t)((kc) + 2 * kp     ) * FDIM);   \
        r1 = *(const uint2*)(xb + (size_t)((kc) + 2 * kp +  1) * FDIM);   \
        r2 = *(const uint2*)(xb + (size_t)((kc) + 2 * kp + 32) * FDIM);   \
        r3 = *(const uint2*)(xb + (size_t)((kc) + 2 * kp + 33) * FDIM);   \
    } while (0)
#define STX(bufi) do {                                                    \
        unsigned* bw = (unsigned*)(Bs[bufi]);                             \
        bw[(4 * g + 0) * 36 + kp]      = (r0.x & 0xffffu) | (r1.x << 16); \
        bw[(4 * g + 1) * 36 + kp]      = (r0.x >> 16) | (r1.x & 0xffff0000u); \
        bw[(4 * g + 2) * 36 + kp]      = (r0.y & 0xffffu) | (r1.y << 16); \
        bw[(4 * g + 3) * 36 + kp]      = (r0.y >> 16) | (r1.y & 0xffff0000u); \
        bw[(4 * g + 0) * 36 + kp + 16] = (r2.x & 0xffffu) | (r3.x << 16); \
        bw[(4 * g + 1) * 36 + kp + 16] = (r2.x >> 16) | (r3.x & 0xffff0000u); \
        bw[(4 * g + 2) * 36 + kp + 16] = (r2.y & 0xffffu) | (r3.y << 16); \
        bw[(4 * g + 3) * 36 + kp + 16] = (r2.y >> 16) | (r3.y & 0xffff0000u); \
    } while (0)

    LDX(0);
    STX(0);

    for (int c = 0; c < 4; ++c) {
        if (c < 3) LDX((c + 1) * 64);          // prefetch next x-chunk
        short8 af[4][2];                       // A-frags (global, L2-hot)
        #pragma unroll
        for (int mf = 0; mf < 4; ++mf)
            #pragma unroll
            for (int h = 0; h < 2; ++h)
                af[mf][h] = *(const short8*)(abb
                    + (size_t)(64 * wv + 16 * mf + n16) * LQ
                    + c * 64 + h * 32 + quad * 8);
        __syncthreads();                       // Bs[c&1] ready; prev reads done
        const ushort* bsc = Bs[c & 1];
        #pragma unroll
        for (int h = 0; h < 2; ++h)
            #pragma unroll
            for (int nf = 0; nf < 4; ++nf) {
                const short8 bf = *(const short8*)(bsc + (16 * nf + n16) * 72
                                                   + h * 32 + quad * 8);
                #pragma unroll
                for (int mf = 0; mf < 4; ++mf)
                    acc[mf][nf] = __builtin_amdgcn_mfma_f32_16x16x32_bf16(
                        af[mf][h], bf, acc[mf][nf], 0, 0, 0);
            }
        if (c < 3) STX((c + 1) & 1);           // fill the other buffer
    }
#undef LDX
#undef STX

    float* ob = out + ((size_t)b * LQ + 64 * wv + quad * 4) * FDIM + f0 + n16;
    #pragma unroll
    for (int mf = 0; mf < 4; ++mf)
        #pragma unroll
        for (int nf = 0; nf < 4; ++nf)
            #pragma unroll
            for (int r = 0; r < 4; ++r)
                ob[(size_t)(16 * mf + r) * FDIM + 16 * nf] = acc[mf][nf][r];
}

// ---------------------------------------------------------------------------
extern "C" void kernel_launch(void* const* d_in, const int* in_sizes, int n_in,
                              void* d_out, int out_size, void* d_ws, size_t ws_size,
                              hipStream_t stream) {
    const float* x  = (const float*)d_in[0];   // [8,256,6272]
    const float* Wt = (const float*)d_in[1];   // [6272,32]
    const float* bh = (const float*)d_in[2];   // [32]
    const float* Wa = (const float*)d_in[3];   // [32,1]
    const float* ba = (const float*)d_in[4];   // [1]
    float* out = (float*)d_out;                // [8,256,6272]

    float*  pb   = (float*)d_ws;                               // 2048*32 fp32   (256 KB)
    ushort* ab   = (ushort*)((char*)d_ws + 262144);            // 8*256*256 bf16 (1 MB)
    ushort* wtt  = (ushort*)((char*)d_ws + 262144 + 1048576);  // 32*6272 bf16   (pad 512K)
    ushort* xb16 = (ushort*)((char*)d_ws + 262144 + 1048576 + 524288); // 25.7 MB

    k_wtt<<<98, 256, 0, stream>>>(Wt, wtt, pb);
    k1_mfma<<<dim3(64, 14), 256, 0, stream>>>(x, wtt, pb, xb16);
    k2_attn<<<dim3(LQ / QG, BN), 256, 0, stream>>>(pb, bh, Wa, ba, ab);
    k3_fused<<<dim3(98, 8), 256, 0, stream>>>(xb16, ab, out);
}